// Round 11
// baseline (287.103 us; speedup 1.0000x reference)
//
#include <hip/hip_runtime.h>
#include <stdint.h>

// B=2, T=2048, C=768, H=12, D=64. All inputs fp32; output fp32.
// Internally: f16 MFMA (16x16x32), fp32 accumulation.
// GEMMs: glds width=16 staging, XOR-swizzled LDS (0 bank conflicts measured).
// ALL GEMMs use XCD-aware 1D grids (r10: MODE2 FETCH 83->31 MB): bid&7 = XCD,
// each XCD owns 4 consecutive m-tiles and sweeps n-tiles back-to-back, so
// A-tiles stay resident in that XCD's private L2.
// MODE0: BK=64 single-buffered. MODE1/2: BK=32 dbuf. MODE2: split-K x4.

typedef __attribute__((ext_vector_type(8))) _Float16 half8;
typedef __attribute__((ext_vector_type(4))) float f32x4;

__device__ inline f32x4 mfma16(half8 a, half8 b, f32x4 c) {
    return __builtin_amdgcn_mfma_f32_16x16x32_f16(a, b, c, 0, 0, 0);
}

__device__ __forceinline__ void gld16(const _Float16* g, _Float16* lds) {
    __builtin_amdgcn_global_load_lds(
        (const __attribute__((address_space(1))) void*)(uintptr_t)g,
        (__attribute__((address_space(3))) void*)(uint32_t)(uintptr_t)lds,
        16, 0, 0);
}

// ---------------- fused prep: LN1 + all three weight repacks ----------------
// blocks [0,4096): ln rows; [4096,5824): qkv repack; [5824,8128): wh; [8128,10432): wp
__global__ __launch_bounds__(256) void prep_kernel(
    const float* __restrict__ x, const float* __restrict__ g, const float* __restrict__ bta,
    _Float16* __restrict__ h1,
    const float* __restrict__ wq, const float* __restrict__ wk, const float* __restrict__ wv,
    _Float16* __restrict__ wqkv,
    const float* __restrict__ w_hidden, _Float16* __restrict__ wh,
    const float* __restrict__ w_proj, _Float16* __restrict__ wp) {
    __shared__ float tile[32][33];
    int bid = blockIdx.x;
    int tid = threadIdx.x;
    if (bid < 4096) {
        int row = bid;
        const float* xr = x + (size_t)row * 768;
        float v[3], s = 0.f, s2 = 0.f;
#pragma unroll
        for (int i = 0; i < 3; i++) { v[i] = xr[tid + i * 256]; s += v[i]; s2 += v[i] * v[i]; }
#pragma unroll
        for (int off = 32; off; off >>= 1) { s += __shfl_down(s, off, 64); s2 += __shfl_down(s2, off, 64); }
        float* red = &tile[0][0];
        int wave = tid >> 6, lane = tid & 63;
        if (lane == 0) { red[wave] = s; red[4 + wave] = s2; }
        __syncthreads();
        if (tid == 0) {
            float ts = red[0] + red[1] + red[2] + red[3];
            float ts2 = red[4] + red[5] + red[6] + red[7];
            float mu = ts * (1.f / 768.f);
            float var = ts2 * (1.f / 768.f) - mu * mu;
            red[0] = mu; red[1] = rsqrtf(var + 1e-5f);
        }
        __syncthreads();
        float mu = red[0], rstd = red[1];
#pragma unroll
        for (int i = 0; i < 3; i++) {
            int c = tid + i * 256;
            h1[(size_t)row * 768 + c] = (_Float16)((v[i] - mu) * rstd * g[c] + bta[c]);
        }
        return;
    }
    int tx = tid & 31, ty = tid >> 5;
    if (bid < 5824) {
        int idx = bid - 4096;
        int y = idx / 24, bx = idx % 24;
        int sel = y / 24, rem = y % 24, h = rem >> 1, dt = rem & 1;
        const float* src = (sel == 0) ? wq : ((sel == 1) ? wk : wv);
        int c0 = bx * 32, d0 = dt * 32;
#pragma unroll
        for (int i = 0; i < 4; i++) {
            int c = ty + i * 8;
            tile[c][tx] = src[((size_t)h * 768 + c0 + c) * 64 + d0 + tx];
        }
        __syncthreads();
#pragma unroll
        for (int i = 0; i < 4; i++) {
            int d = ty + i * 8;
            wqkv[((size_t)(sel * 768 + h * 64 + d0 + d)) * 768 + c0 + tx] = (_Float16)tile[tx][d];
        }
        return;
    }
    const float* w; _Float16* wt; int K, N, idx;
    if (bid < 8128) { idx = bid - 5824; w = w_hidden; wt = wh; K = 768; N = 3072; }
    else            { idx = bid - 8128; w = w_proj;   wt = wp; K = 3072; N = 768; }
    int nb = N / 32;
    int n0 = (idx % nb) * 32, k0 = (idx / nb) * 32;
#pragma unroll
    for (int i = 0; i < 4; i++) {
        int k = ty + i * 8;
        tile[k][tx] = w[(size_t)(k0 + k) * N + n0 + tx];
    }
    __syncthreads();
#pragma unroll
    for (int i = 0; i < 4; i++) {
        int n = ty + i * 8;
        wt[(size_t)(n0 + n) * K + k0 + tx] = (_Float16)tile[tx][n];
    }
}

// x2 = x + attn; h2 = LN(x2); outInit = x2 + b_proj (MODE2 atomicAdds onto it)
__global__ __launch_bounds__(256) void addln_kernel(const float* __restrict__ x,
                                                    const float* __restrict__ attn,
                                                    const float* __restrict__ g,
                                                    const float* __restrict__ bta,
                                                    const float* __restrict__ bproj,
                                                    float* __restrict__ x2,
                                                    _Float16* __restrict__ out,
                                                    float* __restrict__ outInit) {
    int row = blockIdx.x;               // b*2048 + t
    const float* xr = x + (size_t)row * 768;
    const float* ar = attn + (size_t)row * 768;
    int tid = threadIdx.x;
    float v[3], s = 0.f, s2 = 0.f;
#pragma unroll
    for (int i = 0; i < 3; i++) {
        int c = tid + i * 256;
        v[i] = xr[c] + ar[c];
        x2[(size_t)row * 768 + c] = v[i];
        outInit[(size_t)row * 768 + c] = v[i] + bproj[c];
        s += v[i]; s2 += v[i] * v[i];
    }
#pragma unroll
    for (int off = 32; off; off >>= 1) { s += __shfl_down(s, off, 64); s2 += __shfl_down(s2, off, 64); }
    __shared__ float red[8];
    int wave = tid >> 6, lane = tid & 63;
    if (lane == 0) { red[wave] = s; red[4 + wave] = s2; }
    __syncthreads();
    if (tid == 0) {
        float ts = red[0] + red[1] + red[2] + red[3];
        float ts2 = red[4] + red[5] + red[6] + red[7];
        float mu = ts * (1.f / 768.f);
        float var = ts2 * (1.f / 768.f) - mu * mu;
        red[0] = mu; red[1] = rsqrtf(var + 1e-5f);
    }
    __syncthreads();
    float mu = red[0], rstd = red[1];
#pragma unroll
    for (int i = 0; i < 3; i++) {
        int c = tid + i * 256;
        out[(size_t)row * 768 + c] = (_Float16)((v[i] - mu) * rstd * g[c] + bta[c]);
    }
}

// ---------------- MFMA GEMM 128x128 tile, templated BK/DBUF, glds staging ----------------
// BK=32: row = 4 chunks of 16B, phys chunk = c ^ ((row>>1)&3)   (r3: 0 conflicts)
// BK=64: row = 8 chunks of 16B, phys chunk = c ^ (row&7)        (r5: 0 conflicts)
// 1D XCD grid: bid&7 = XCD; s=bid>>3; z = s/(4*NT) split-K part;
// rem = s%(4*NT): m-tile = xcd*4 + rem/NT, n-tile = rem%NT.
// MODE 0: scatter q(b,h,t,d)[*1/sqrt(768)], k(b,h,t,d), vt(b,h,d,t)  (N=2304)
// MODE 1: +bias, relu -> f16 out [M][N]
// MODE 2: split-K x4, atomicAdd into outF (pre-initialized)
template <int MODE, int BK, bool DBUF, int NT, int KSPLIT>
__global__ __launch_bounds__(256) void gemm_kernel(
    const _Float16* __restrict__ A, const _Float16* __restrict__ Bt, int N, int K,
    const float* __restrict__ bias, float* __restrict__ outF, _Float16* __restrict__ outH,
    _Float16* __restrict__ qb, _Float16* __restrict__ kb, _Float16* __restrict__ vtb) {
    constexpr int NBUF = DBUF ? 2 : 1;
    __shared__ __align__(16) _Float16 As[NBUF][128 * BK];
    __shared__ __align__(16) _Float16 Bs[NBUF][128 * BK];
    const int tid = threadIdx.x;
    const int wave = tid >> 6, lane = tid & 63;

    const int bid = blockIdx.x;
    const int xcd = bid & 7, s = bid >> 3;
    const int z = s / (4 * NT), rem = s % (4 * NT);
    const int m0 = (xcd * 4 + rem / NT) * 128;
    const int n0 = (rem % NT) * 128;
    const int kLen = K / KSPLIT;
    const int kbeg = z * kLen;

    const int wm = (wave >> 1) * 64, wn = (wave & 1) * 64;
    const int lr = lane & 15, lq = lane >> 4;
    const int nIter = kLen / BK;

    auto stage = [&](int k0, int bsel) {
        if constexpr (BK == 32) {
            const int sr = lane >> 2;
            const int sc = (lane & 3) ^ ((lane >> 3) & 3);
#pragma unroll
            for (int t = 0; t < 2; ++t) {
                int row = wave * 32 + t * 16;
                gld16(&A[(size_t)(m0 + row + sr) * K + k0 + sc * 8], &As[bsel][row * 32]);
                gld16(&Bt[(size_t)(n0 + row + sr) * K + k0 + sc * 8], &Bs[bsel][row * 32]);
            }
        } else {
            const int sr = lane >> 3;
            const int sc = (lane & 7) ^ sr;
#pragma unroll
            for (int t = 0; t < 4; ++t) {
                int row = wave * 32 + t * 8;
                gld16(&A[(size_t)(m0 + row + sr) * K + k0 + sc * 8], &As[bsel][row * 64]);
                gld16(&Bt[(size_t)(n0 + row + sr) * K + k0 + sc * 8], &Bs[bsel][row * 64]);
            }
        }
    };

    auto compute = [&](int bsel, f32x4 (&acc)[4][4]) {
#pragma unroll
        for (int ks = 0; ks < BK / 32; ++ks) {
            half8 af[4], bf[4];
#pragma unroll
            for (int i = 0; i < 4; i++) {
                int cs = (BK == 32) ? ((lq ^ ((lr >> 1) & 3)) * 8)
                                    : (((ks * 4 + lq) ^ (lr & 7)) * 8);
                af[i] = *(const half8*)&As[bsel][(wm + i * 16 + lr) * BK + cs];
            }
#pragma unroll
            for (int j = 0; j < 4; j++) {
                int cs = (BK == 32) ? ((lq ^ ((lr >> 1) & 3)) * 8)
                                    : (((ks * 4 + lq) ^ (lr & 7)) * 8);
                bf[j] = *(const half8*)&Bs[bsel][(wn + j * 16 + lr) * BK + cs];
            }
#pragma unroll
            for (int i = 0; i < 4; i++)
#pragma unroll
                for (int j = 0; j < 4; j++)
                    acc[i][j] = mfma16(af[i], bf[j], acc[i][j]);
        }
    };

    f32x4 acc[4][4] = {};

    if constexpr (DBUF) {
        stage(kbeg, 0);
        for (int it = 0; it < nIter; ++it) {
            __syncthreads();                 // drains prefetch of tile it
            if (it + 1 < nIter) stage(kbeg + (it + 1) * BK, (it + 1) & 1);
            compute(it & 1, acc);
        }
    } else {
        for (int it = 0; it < nIter; ++it) {
            stage(kbeg + it * BK, 0);
            __syncthreads();
            compute(0, acc);
            __syncthreads();
        }
    }

    const float qscale = 0.03608439182435161f;  // 1/sqrt(768)
#pragma unroll
    for (int i = 0; i < 4; i++) {
#pragma unroll
        for (int j = 0; j < 4; j++) {
            int n = n0 + wn + j * 16 + lr;
            int mb = m0 + wm + i * 16 + lq * 4;
#pragma unroll
            for (int r = 0; r < 4; r++) {
                int m = mb + r;
                float v = acc[i][j][r];
                if constexpr (MODE == 0) {
                    int b = m >> 11, t = m & 2047;
                    int sel = n / 768, nn = n % 768;
                    int h = nn >> 6, d = nn & 63;
                    size_t bh = (size_t)(b * 12 + h);
                    if (sel == 0)      qb[(bh * 2048 + t) * 64 + d] = (_Float16)(v * qscale);
                    else if (sel == 1) kb[(bh * 2048 + t) * 64 + d] = (_Float16)v;
                    else               vtb[(bh * 64 + d) * 2048 + t] = (_Float16)v;
                } else if constexpr (MODE == 1) {
                    v += bias[n];
                    v = v > 0.f ? v : 0.f;
                    outH[(size_t)m * N + n] = (_Float16)v;
                } else {
                    atomicAdd(&outF[(size_t)m * N + n], v);
                }
            }
        }
    }
}

// ---------------- flash attention (causal), dbuf 64-wide KV, no atomics ----------------
__global__ __launch_bounds__(256) void attn_kernel(const _Float16* __restrict__ qb,
                                                   const _Float16* __restrict__ kb,
                                                   const _Float16* __restrict__ vtb,
                                                   float* __restrict__ attn_out) {
    const int qt = 31 - blockIdx.x;   // heavy tiles first
    const int bh = blockIdx.y;
    const int b = bh / 12, h = bh % 12;
    const int q0 = qt * 64;

    __shared__ __align__(16) _Float16 Ks[2][64 * 64];
    __shared__ __align__(16) _Float16 Vs[2][64 * 64];
    __shared__ __align__(16) _Float16 Ps[4][16 * 72];
    const int tid = threadIdx.x, wave = tid >> 6, lane = tid & 63;
    const int lr = lane & 15, lq = lane >> 4;
    const int sr = lane >> 3;            // staging row within 8
    const int sc = (lane & 7) ^ sr;      // swizzled chunk
    const _Float16* qbase = qb + (size_t)bh * 2048 * 64;
    const _Float16* kbase = kb + (size_t)bh * 2048 * 64;
    const _Float16* vbase = vtb + (size_t)bh * 64 * 2048;

    half8 qf[2];
#pragma unroll
    for (int kd2 = 0; kd2 < 2; kd2++)
        qf[kd2] = *(const half8*)&qbase[(size_t)(q0 + wave * 16 + lr) * 64 + kd2 * 32 + lq * 8];

    auto stageKV = [&](int tile, int bsel) {
        int kv0 = tile << 6;
#pragma unroll
        for (int u = 0; u < 2; ++u) {
            int row0 = wave * 16 + u * 8;
            gld16(&kbase[(size_t)(kv0 + row0 + sr) * 64 + sc * 8], &Ks[bsel][row0 * 64]);
            gld16(&vbase[(size_t)(row0 + sr) * 2048 + kv0 + sc * 8], &Vs[bsel][row0 * 64]);
        }
    };

    f32x4 O[4] = {};
    float lsum[4] = {0.f, 0.f, 0.f, 0.f};
    const int nT = qt + 1;
    stageKV(0, 0);

    for (int t = 0; t < nT; ++t) {
        __syncthreads();                      // drains glds for tile t
        if (t + 1 < nT) stageKV(t + 1, (t + 1) & 1);
        const int bs = t & 1, kv0 = t << 6;
        const bool mask = (t == qt);

        f32x4 S[4] = {};
#pragma unroll
        for (int kd2 = 0; kd2 < 2; kd2++) {
#pragma unroll
            for (int nf = 0; nf < 4; nf++) {
                half8 bk = *(const half8*)&Ks[bs][(nf * 16 + lr) * 64 +
                                                  (((kd2 * 4 + lq) ^ (lr & 7)) * 8)];
                S[nf] = mfma16(qf[kd2], bk, S[nf]);
            }
        }

        const int qi_base = q0 + wave * 16 + lq * 4;
#pragma unroll
        for (int r = 0; r < 4; r++) {
            float a = 0.f;
#pragma unroll
            for (int nf = 0; nf < 4; nf++) {
                float p = __expf(S[nf][r]);
                if (mask) {
                    int j = kv0 + nf * 16 + lr;
                    if (j > qi_base + r) p = 0.f;
                }
                a += p;
                Ps[wave][(lq * 4 + r) * 72 + nf * 16 + lr] = (_Float16)p;
            }
            lsum[r] += a;
        }

#pragma unroll
        for (int ks = 0; ks < 2; ks++) {
            half8 ap = *(const half8*)&Ps[wave][lr * 72 + ks * 32 + lq * 8];
#pragma unroll
            for (int df = 0; df < 4; df++) {
                half8 bv = *(const half8*)&Vs[bs][(df * 16 + lr) * 64 +
                                                  (((ks * 4 + lq) ^ (lr & 7)) * 8)];
                O[df] = mfma16(ap, bv, O[df]);
            }
        }
    }

#pragma unroll
    for (int r = 0; r < 4; r++) {
#pragma unroll
        for (int off = 1; off < 16; off <<= 1) lsum[r] += __shfl_xor(lsum[r], off, 64);
    }

#pragma unroll
    for (int df = 0; df < 4; df++) {
#pragma unroll
        for (int r = 0; r < 4; r++) {
            int t = q0 + wave * 16 + lq * 4 + r;
            int d = df * 16 + lr;
            attn_out[((size_t)b * 2048 + t) * 768 + h * 64 + d] = O[df][r] / lsum[r];
        }
    }
}

extern "C" void kernel_launch(void* const* d_in, const int* in_sizes, int n_in,
                              void* d_out, int out_size, void* d_ws, size_t ws_size,
                              hipStream_t stream) {
    (void)in_sizes; (void)n_in; (void)out_size; (void)ws_size;
    const float* x        = (const float*)d_in[0];
    const float* ln1_g    = (const float*)d_in[1];
    const float* ln1_b    = (const float*)d_in[2];
    const float* wq       = (const float*)d_in[3];
    const float* wk       = (const float*)d_in[4];
    const float* wv       = (const float*)d_in[5];
    const float* ln2_g    = (const float*)d_in[6];
    const float* ln2_b    = (const float*)d_in[7];
    const float* w_hidden = (const float*)d_in[8];
    const float* b_hidden = (const float*)d_in[9];
    const float* w_proj   = (const float*)d_in[10];
    const float* b_proj   = (const float*)d_in[11];
    float* out = (float*)d_out;

    uint8_t* p = (uint8_t*)d_ws;
    _Float16* h1   = (_Float16*)p; p += 4096ull * 768 * 2;
    _Float16* wqkv = (_Float16*)p; p += 2304ull * 768 * 2;
    _Float16* wh   = (_Float16*)p; p += 3072ull * 768 * 2;
    _Float16* wp   = (_Float16*)p; p += 768ull * 3072 * 2;
    _Float16* qb   = (_Float16*)p; p += 24ull * 2048 * 64 * 2;
    _Float16* kb   = (_Float16*)p; p += 24ull * 2048 * 64 * 2;
    _Float16* vtb  = (_Float16*)p; p += 24ull * 2048 * 64 * 2;
    float*    attn = (float*)p;    p += 4096ull * 768 * 4;
    float*    x2   = (float*)p;    p += 4096ull * 768 * 4;
    _Float16* h2   = (_Float16*)p; p += 4096ull * 768 * 2;
    _Float16* hid  = (_Float16*)p; p += 4096ull * 3072 * 2;

    prep_kernel<<<10432, 256, 0, stream>>>(x, ln1_g, ln1_b, h1,
        wq, wk, wv, wqkv, w_hidden, wh, w_proj, wp);
    // MODE0: 32m x 18n tiles, XCD-swizzled 1D grid 576
    gemm_kernel<0, 64, false, 18, 1><<<576, 256, 0, stream>>>(h1, wqkv, 2304, 768,
        nullptr, nullptr, nullptr, qb, kb, vtb);
    attn_kernel<<<dim3(32, 24), 256, 0, stream>>>(qb, kb, vtb, attn);
    addln_kernel<<<4096, 256, 0, stream>>>(x, attn, ln2_g, ln2_b, b_proj, x2, h2, out);
    // MODE1: 32m x 24n tiles, XCD-swizzled 1D grid 768
    gemm_kernel<1, 32, true, 24, 1><<<768, 256, 0, stream>>>(h2, wh, 3072, 768,
        b_hidden, nullptr, hid, nullptr, nullptr, nullptr);
    // MODE2: 32m x 6n tiles x splitK4, XCD-swizzled 1D grid 768
    gemm_kernel<2, 32, true, 6, 4><<<768, 256, 0, stream>>>(hid, wp, 768, 3072,
        nullptr, out, nullptr, nullptr, nullptr, nullptr);
}

// Round 12
// 274.312 us; speedup vs baseline: 1.0466x; 1.0466x over previous
//
#include <hip/hip_runtime.h>
#include <stdint.h>

// B=2, T=2048, C=768, H=12, D=64. All inputs fp32; output fp32.
// Internally: f16 MFMA (16x16x32), fp32 accumulation.
// GEMMs: glds width=16 staging, XOR-swizzled LDS (0 bank conflicts measured),
// XCD-aware 1D grids (r10: FETCH 83->31 MB on MODE2).
// MODE2 (r12): 64x64 tiles, KSPLIT=1, NO ATOMICS — r6/r7 A/B showed float
// atomics cost ~0.74us/MB (~37us of MODE2's 62us). Direct epilogue
// out = acc + b_proj + x2. 768 blocks = 3/CU without split-K.

typedef __attribute__((ext_vector_type(8))) _Float16 half8;
typedef __attribute__((ext_vector_type(4))) float f32x4;

__device__ inline f32x4 mfma16(half8 a, half8 b, f32x4 c) {
    return __builtin_amdgcn_mfma_f32_16x16x32_f16(a, b, c, 0, 0, 0);
}

__device__ __forceinline__ void gld16(const _Float16* g, _Float16* lds) {
    __builtin_amdgcn_global_load_lds(
        (const __attribute__((address_space(1))) void*)(uintptr_t)g,
        (__attribute__((address_space(3))) void*)(uint32_t)(uintptr_t)lds,
        16, 0, 0);
}

// ---------------- fused prep: LN1 + all three weight repacks ----------------
// blocks [0,4096): ln rows; [4096,5824): qkv repack; [5824,8128): wh; [8128,10432): wp
__global__ __launch_bounds__(256) void prep_kernel(
    const float* __restrict__ x, const float* __restrict__ g, const float* __restrict__ bta,
    _Float16* __restrict__ h1,
    const float* __restrict__ wq, const float* __restrict__ wk, const float* __restrict__ wv,
    _Float16* __restrict__ wqkv,
    const float* __restrict__ w_hidden, _Float16* __restrict__ wh,
    const float* __restrict__ w_proj, _Float16* __restrict__ wp) {
    __shared__ float tile[32][33];
    int bid = blockIdx.x;
    int tid = threadIdx.x;
    if (bid < 4096) {
        int row = bid;
        const float* xr = x + (size_t)row * 768;
        float v[3], s = 0.f, s2 = 0.f;
#pragma unroll
        for (int i = 0; i < 3; i++) { v[i] = xr[tid + i * 256]; s += v[i]; s2 += v[i] * v[i]; }
#pragma unroll
        for (int off = 32; off; off >>= 1) { s += __shfl_down(s, off, 64); s2 += __shfl_down(s2, off, 64); }
        float* red = &tile[0][0];
        int wave = tid >> 6, lane = tid & 63;
        if (lane == 0) { red[wave] = s; red[4 + wave] = s2; }
        __syncthreads();
        if (tid == 0) {
            float ts = red[0] + red[1] + red[2] + red[3];
            float ts2 = red[4] + red[5] + red[6] + red[7];
            float mu = ts * (1.f / 768.f);
            float var = ts2 * (1.f / 768.f) - mu * mu;
            red[0] = mu; red[1] = rsqrtf(var + 1e-5f);
        }
        __syncthreads();
        float mu = red[0], rstd = red[1];
#pragma unroll
        for (int i = 0; i < 3; i++) {
            int c = tid + i * 256;
            h1[(size_t)row * 768 + c] = (_Float16)((v[i] - mu) * rstd * g[c] + bta[c]);
        }
        return;
    }
    int tx = tid & 31, ty = tid >> 5;
    if (bid < 5824) {
        int idx = bid - 4096;
        int y = idx / 24, bx = idx % 24;
        int sel = y / 24, rem = y % 24, h = rem >> 1, dt = rem & 1;
        const float* src = (sel == 0) ? wq : ((sel == 1) ? wk : wv);
        int c0 = bx * 32, d0 = dt * 32;
#pragma unroll
        for (int i = 0; i < 4; i++) {
            int c = ty + i * 8;
            tile[c][tx] = src[((size_t)h * 768 + c0 + c) * 64 + d0 + tx];
        }
        __syncthreads();
#pragma unroll
        for (int i = 0; i < 4; i++) {
            int d = ty + i * 8;
            wqkv[((size_t)(sel * 768 + h * 64 + d0 + d)) * 768 + c0 + tx] = (_Float16)tile[tx][d];
        }
        return;
    }
    const float* w; _Float16* wt; int K, N, idx;
    if (bid < 8128) { idx = bid - 5824; w = w_hidden; wt = wh; K = 768; N = 3072; }
    else            { idx = bid - 8128; w = w_proj;   wt = wp; K = 3072; N = 768; }
    int nb = N / 32;
    int n0 = (idx % nb) * 32, k0 = (idx / nb) * 32;
#pragma unroll
    for (int i = 0; i < 4; i++) {
        int k = ty + i * 8;
        tile[k][tx] = w[(size_t)(k0 + k) * N + n0 + tx];
    }
    __syncthreads();
#pragma unroll
    for (int i = 0; i < 4; i++) {
        int n = ty + i * 8;
        wt[(size_t)(n0 + n) * K + k0 + tx] = (_Float16)tile[tx][n];
    }
}

// x2 = x + attn; h2 = LN(x2)   (x2 is MODE2's residual input)
__global__ __launch_bounds__(256) void addln_kernel(const float* __restrict__ x,
                                                    const float* __restrict__ attn,
                                                    const float* __restrict__ g,
                                                    const float* __restrict__ bta,
                                                    float* __restrict__ x2,
                                                    _Float16* __restrict__ out) {
    int row = blockIdx.x;               // b*2048 + t
    const float* xr = x + (size_t)row * 768;
    const float* ar = attn + (size_t)row * 768;
    int tid = threadIdx.x;
    float v[3], s = 0.f, s2 = 0.f;
#pragma unroll
    for (int i = 0; i < 3; i++) {
        int c = tid + i * 256;
        v[i] = xr[c] + ar[c];
        x2[(size_t)row * 768 + c] = v[i];
        s += v[i]; s2 += v[i] * v[i];
    }
#pragma unroll
    for (int off = 32; off; off >>= 1) { s += __shfl_down(s, off, 64); s2 += __shfl_down(s2, off, 64); }
    __shared__ float red[8];
    int wave = tid >> 6, lane = tid & 63;
    if (lane == 0) { red[wave] = s; red[4 + wave] = s2; }
    __syncthreads();
    if (tid == 0) {
        float ts = red[0] + red[1] + red[2] + red[3];
        float ts2 = red[4] + red[5] + red[6] + red[7];
        float mu = ts * (1.f / 768.f);
        float var = ts2 * (1.f / 768.f) - mu * mu;
        red[0] = mu; red[1] = rsqrtf(var + 1e-5f);
    }
    __syncthreads();
    float mu = red[0], rstd = red[1];
#pragma unroll
    for (int i = 0; i < 3; i++) {
        int c = tid + i * 256;
        out[(size_t)row * 768 + c] = (_Float16)((v[i] - mu) * rstd * g[c] + bta[c]);
    }
}

// ---------------- MFMA GEMM BMxBN tile, BK=32, glds staging ----------------
// LDS: row = 4 chunks of 16B, phys chunk = c ^ ((row>>1)&3)  (0 conflicts, r3).
// 1D XCD grid: xcd = bid&7; s = bid>>3; m-tile = xcd*MPX + s/NT; n-tile = s%NT.
// MODE 0 (128x128): scatter q(b,h,t,d)[*1/sqrt(768)], k(b,h,t,d), vt(b,h,d,t)
// MODE 1 (128x128): +bias, relu -> f16 out [M][N]
// MODE 2 (64x64):   +bias +resid -> f32 out [M][N], no atomics, KSPLIT=1
template <int MODE, bool DBUF, int BM, int BN, int NT, int MPX>
__global__ __launch_bounds__(256) void gemm_kernel(
    const _Float16* __restrict__ A, const _Float16* __restrict__ Bt, int N, int K,
    const float* __restrict__ bias, const float* __restrict__ resid,
    float* __restrict__ outF, _Float16* __restrict__ outH,
    _Float16* __restrict__ qb, _Float16* __restrict__ kb, _Float16* __restrict__ vtb) {
    constexpr int BK = 32;
    constexpr int NBUF = DBUF ? 2 : 1;
    constexpr int IM = BM / 32, JN = BN / 32;
    __shared__ __align__(16) _Float16 As[NBUF][BM * BK];
    __shared__ __align__(16) _Float16 Bs[NBUF][BN * BK];
    const int tid = threadIdx.x;
    const int wave = tid >> 6, lane = tid & 63;

    const int bid = blockIdx.x;
    const int xcd = bid & 7, s = bid >> 3;
    const int m0 = (xcd * MPX + s / NT) * BM;
    const int n0 = (s % NT) * BN;

    const int wm = (wave >> 1) * (BM / 2), wn = (wave & 1) * (BN / 2);
    const int lr = lane & 15, lq = lane >> 4;
    const int nIter = K / BK;

    auto stage = [&](int k0, int bsel) {
        const int sr = lane >> 2;
        const int sc = (lane & 3) ^ ((lane >> 3) & 3);
#pragma unroll
        for (int t = 0; t < BM / 64; ++t) {
            int row = wave * (BM / 4) + t * 16;
            gld16(&A[(size_t)(m0 + row + sr) * K + k0 + sc * 8], &As[bsel][row * 32]);
        }
#pragma unroll
        for (int t = 0; t < BN / 64; ++t) {
            int row = wave * (BN / 4) + t * 16;
            gld16(&Bt[(size_t)(n0 + row + sr) * K + k0 + sc * 8], &Bs[bsel][row * 32]);
        }
    };

    auto compute = [&](int bsel, f32x4 (&acc)[IM][JN]) {
        half8 af[IM], bf[JN];
        const int cs = (lq ^ ((lr >> 1) & 3)) * 8;
#pragma unroll
        for (int i = 0; i < IM; i++) af[i] = *(const half8*)&As[bsel][(wm + i * 16 + lr) * 32 + cs];
#pragma unroll
        for (int j = 0; j < JN; j++) bf[j] = *(const half8*)&Bs[bsel][(wn + j * 16 + lr) * 32 + cs];
#pragma unroll
        for (int i = 0; i < IM; i++)
#pragma unroll
            for (int j = 0; j < JN; j++)
                acc[i][j] = mfma16(af[i], bf[j], acc[i][j]);
    };

    f32x4 acc[IM][JN] = {};

    if constexpr (DBUF) {
        stage(0, 0);
        for (int it = 0; it < nIter; ++it) {
            __syncthreads();                 // drains prefetch of tile it
            if (it + 1 < nIter) stage((it + 1) * BK, (it + 1) & 1);
            compute(it & 1, acc);
        }
    } else {
        for (int it = 0; it < nIter; ++it) {
            stage(it * BK, 0);
            __syncthreads();
            compute(0, acc);
            __syncthreads();
        }
    }

    const float qscale = 0.03608439182435161f;  // 1/sqrt(768)
#pragma unroll
    for (int i = 0; i < IM; i++) {
#pragma unroll
        for (int j = 0; j < JN; j++) {
            int n = n0 + wn + j * 16 + lr;
            int mb = m0 + wm + i * 16 + lq * 4;
#pragma unroll
            for (int r = 0; r < 4; r++) {
                int m = mb + r;
                float v = acc[i][j][r];
                if constexpr (MODE == 0) {
                    int b = m >> 11, t = m & 2047;
                    int sel = n / 768, nn = n % 768;
                    int h = nn >> 6, d = nn & 63;
                    size_t bh = (size_t)(b * 12 + h);
                    if (sel == 0)      qb[(bh * 2048 + t) * 64 + d] = (_Float16)(v * qscale);
                    else if (sel == 1) kb[(bh * 2048 + t) * 64 + d] = (_Float16)v;
                    else               vtb[(bh * 64 + d) * 2048 + t] = (_Float16)v;
                } else if constexpr (MODE == 1) {
                    v += bias[n];
                    v = v > 0.f ? v : 0.f;
                    outH[(size_t)m * N + n] = (_Float16)v;
                } else {
                    v += bias[n] + resid[(size_t)m * N + n];
                    outF[(size_t)m * N + n] = v;
                }
            }
        }
    }
}

// ---------------- flash attention (causal), dbuf 64-wide KV, no atomics ----------------
__global__ __launch_bounds__(256) void attn_kernel(const _Float16* __restrict__ qb,
                                                   const _Float16* __restrict__ kb,
                                                   const _Float16* __restrict__ vtb,
                                                   float* __restrict__ attn_out) {
    const int qt = 31 - blockIdx.x;   // heavy tiles first
    const int bh = blockIdx.y;
    const int b = bh / 12, h = bh % 12;
    const int q0 = qt * 64;

    __shared__ __align__(16) _Float16 Ks[2][64 * 64];
    __shared__ __align__(16) _Float16 Vs[2][64 * 64];
    __shared__ __align__(16) _Float16 Ps[4][16 * 72];
    const int tid = threadIdx.x, wave = tid >> 6, lane = tid & 63;
    const int lr = lane & 15, lq = lane >> 4;
    const int sr = lane >> 3;            // staging row within 8
    const int sc = (lane & 7) ^ sr;      // swizzled chunk
    const _Float16* qbase = qb + (size_t)bh * 2048 * 64;
    const _Float16* kbase = kb + (size_t)bh * 2048 * 64;
    const _Float16* vbase = vtb + (size_t)bh * 64 * 2048;

    half8 qf[2];
#pragma unroll
    for (int kd2 = 0; kd2 < 2; kd2++)
        qf[kd2] = *(const half8*)&qbase[(size_t)(q0 + wave * 16 + lr) * 64 + kd2 * 32 + lq * 8];

    auto stageKV = [&](int tile, int bsel) {
        int kv0 = tile << 6;
#pragma unroll
        for (int u = 0; u < 2; ++u) {
            int row0 = wave * 16 + u * 8;
            gld16(&kbase[(size_t)(kv0 + row0 + sr) * 64 + sc * 8], &Ks[bsel][row0 * 64]);
            gld16(&vbase[(size_t)(row0 + sr) * 2048 + kv0 + sc * 8], &Vs[bsel][row0 * 64]);
        }
    };

    f32x4 O[4] = {};
    float lsum[4] = {0.f, 0.f, 0.f, 0.f};
    const int nT = qt + 1;
    stageKV(0, 0);

    for (int t = 0; t < nT; ++t) {
        __syncthreads();                      // drains glds for tile t
        if (t + 1 < nT) stageKV(t + 1, (t + 1) & 1);
        const int bs = t & 1, kv0 = t << 6;
        const bool mask = (t == qt);

        f32x4 S[4] = {};
#pragma unroll
        for (int kd2 = 0; kd2 < 2; kd2++) {
#pragma unroll
            for (int nf = 0; nf < 4; nf++) {
                half8 bk = *(const half8*)&Ks[bs][(nf * 16 + lr) * 64 +
                                                  (((kd2 * 4 + lq) ^ (lr & 7)) * 8)];
                S[nf] = mfma16(qf[kd2], bk, S[nf]);
            }
        }

        const int qi_base = q0 + wave * 16 + lq * 4;
#pragma unroll
        for (int r = 0; r < 4; r++) {
            float a = 0.f;
#pragma unroll
            for (int nf = 0; nf < 4; nf++) {
                float p = __expf(S[nf][r]);
                if (mask) {
                    int j = kv0 + nf * 16 + lr;
                    if (j > qi_base + r) p = 0.f;
                }
                a += p;
                Ps[wave][(lq * 4 + r) * 72 + nf * 16 + lr] = (_Float16)p;
            }
            lsum[r] += a;
        }

#pragma unroll
        for (int ks = 0; ks < 2; ks++) {
            half8 ap = *(const half8*)&Ps[wave][lr * 72 + ks * 32 + lq * 8];
#pragma unroll
            for (int df = 0; df < 4; df++) {
                half8 bv = *(const half8*)&Vs[bs][(df * 16 + lr) * 64 +
                                                  (((ks * 4 + lq) ^ (lr & 7)) * 8)];
                O[df] = mfma16(ap, bv, O[df]);
            }
        }
    }

#pragma unroll
    for (int r = 0; r < 4; r++) {
#pragma unroll
        for (int off = 1; off < 16; off <<= 1) lsum[r] += __shfl_xor(lsum[r], off, 64);
    }

#pragma unroll
    for (int df = 0; df < 4; df++) {
#pragma unroll
        for (int r = 0; r < 4; r++) {
            int t = q0 + wave * 16 + lq * 4 + r;
            int d = df * 16 + lr;
            attn_out[((size_t)b * 2048 + t) * 768 + h * 64 + d] = O[df][r] / lsum[r];
        }
    }
}

extern "C" void kernel_launch(void* const* d_in, const int* in_sizes, int n_in,
                              void* d_out, int out_size, void* d_ws, size_t ws_size,
                              hipStream_t stream) {
    (void)in_sizes; (void)n_in; (void)out_size; (void)ws_size;
    const float* x        = (const float*)d_in[0];
    const float* ln1_g    = (const float*)d_in[1];
    const float* ln1_b    = (const float*)d_in[2];
    const float* wq       = (const float*)d_in[3];
    const float* wk       = (const float*)d_in[4];
    const float* wv       = (const float*)d_in[5];
    const float* ln2_g    = (const float*)d_in[6];
    const float* ln2_b    = (const float*)d_in[7];
    const float* w_hidden = (const float*)d_in[8];
    const float* b_hidden = (const float*)d_in[9];
    const float* w_proj   = (const float*)d_in[10];
    const float* b_proj   = (const float*)d_in[11];
    float* out = (float*)d_out;

    uint8_t* p = (uint8_t*)d_ws;
    _Float16* h1   = (_Float16*)p; p += 4096ull * 768 * 2;
    _Float16* wqkv = (_Float16*)p; p += 2304ull * 768 * 2;
    _Float16* wh   = (_Float16*)p; p += 3072ull * 768 * 2;
    _Float16* wp   = (_Float16*)p; p += 768ull * 3072 * 2;
    _Float16* qb   = (_Float16*)p; p += 24ull * 2048 * 64 * 2;
    _Float16* kb   = (_Float16*)p; p += 24ull * 2048 * 64 * 2;
    _Float16* vtb  = (_Float16*)p; p += 24ull * 2048 * 64 * 2;
    float*    attn = (float*)p;    p += 4096ull * 768 * 4;
    float*    x2   = (float*)p;    p += 4096ull * 768 * 4;
    _Float16* h2   = (_Float16*)p; p += 4096ull * 768 * 2;
    _Float16* hid  = (_Float16*)p; p += 4096ull * 3072 * 2;

    prep_kernel<<<10432, 256, 0, stream>>>(x, ln1_g, ln1_b, h1,
        wq, wk, wv, wqkv, w_hidden, wh, w_proj, wp);
    // MODE0: 32m x 18n (128x128), XCD 1D grid 576
    gemm_kernel<0, false, 128, 128, 18, 4><<<576, 256, 0, stream>>>(h1, wqkv, 2304, 768,
        nullptr, nullptr, nullptr, nullptr, qb, kb, vtb);
    attn_kernel<<<dim3(32, 24), 256, 0, stream>>>(qb, kb, vtb, attn);
    addln_kernel<<<4096, 256, 0, stream>>>(x, attn, ln2_g, ln2_b, x2, h2);
    // MODE1: 32m x 24n (128x128), XCD 1D grid 768
    gemm_kernel<1, true, 128, 128, 24, 4><<<768, 256, 0, stream>>>(h2, wh, 3072, 768,
        b_hidden, nullptr, nullptr, hid, nullptr, nullptr, nullptr);
    // MODE2: 64m x 12n (64x64), KSPLIT=1, no atomics, XCD 1D grid 768
    gemm_kernel<2, true, 64, 64, 12, 8><<<768, 256, 0, stream>>>(hid, wp, 768, 3072,
        b_proj, x2, out, nullptr, nullptr, nullptr, nullptr);
}